// Round 5
// baseline (185.498 us; speedup 1.0000x reference)
//
#include <hip/hip_runtime.h>
#include <math.h>

// Problem constants (from reference setup_inputs)
#define BS 4
#define C  3
#define D  8
#define K  10
#define K1 11
#define H  128
#define W  128
#define HW (H*W)

// 4-byte-aligned float4 for unaligned-window vector loads.
typedef float float4a __attribute__((ext_vector_type(4), aligned(4)));
// 16-byte-aligned ext-vector float4 for nontemporal stores
// (__builtin_nontemporal_store rejects HIP_vector_type structs).
typedef float f4 __attribute__((ext_vector_type(4)));

__device__ __forceinline__ void nt_store4(float* p, float a, float b, float c, float d) {
    f4 v = {a, b, c, d};
    __builtin_nontemporal_store(v, (f4*)p);
}

// Single fused kernel.
// blockIdx.y = (b*D+di)*K1 + k  (slot; kp data block-uniform)
// blockIdx.x = row-group (16 rows per block), 256 threads, 8 px/thread.
// Thread map: LINEAR pixels (p = tid*8) -> a wave covers 4 complete rows,
// so every per-channel store burst is 2048 B contiguous (max coalescing).
// All 12 output stores are NONTEMPORAL: the 138 MB output stream is never
// re-read and vastly exceeds the 32 MB aggregate L2 -> bypass write-allocate.
// Phase 1 computes exp_x[128], exp_y[128] and the separable norm in LDS.
__global__ __launch_bounds__(256) void memb_fused_kernel(
        const float* __restrict__ src,
        const float* __restrict__ kpd,
        const float* __restrict__ kps,
        float* __restrict__ out) {
    __shared__ __align__(16) float s_expx[128];
    __shared__ __align__(16) float s_expy[128];
    __shared__ float s_red[4];
    __shared__ float s_nrm;

    int rk = blockIdx.y;               // 0 .. BS*D*K1-1
    int k  = rk % K1;
    int r  = rk / K1;                  // b*D + di
    int di = r & (D - 1);
    int b  = r >> 3;

    float kx = 0.f, ky = 0.f, dx = 0.f, dy = 0.f;
    if (k > 0) {
        int kidx = r * K + (k - 1);
        kx = kpd[kidx * 2 + 0];
        ky = kpd[kidx * 2 + 1];
        dx = kps[kidx * 2 + 0] - kx;
        dy = kps[kidx * 2 + 1] - ky;
    }

    int tid = threadIdx.x;

    // ---- Phase 1: Gaussian tables + normalization (separable) ----
    {
        int j = tid & 127;
        float coord = (float)j * (2.0f / 127.0f) - 1.0f;
        float dd = coord - ((tid < 128) ? kx : ky);
        float e = __expf(-50.0f * dd * dd);
        if (tid < 128) s_expx[j] = e;
        else           s_expy[j] = e;
        #pragma unroll
        for (int o = 32; o > 0; o >>= 1) e += __shfl_down(e, o, 64);
        if ((tid & 63) == 0) s_red[tid >> 6] = e;
    }
    __syncthreads();
    if (tid == 0) {
        float sumx = s_red[0] + s_red[1];
        float sumy = s_red[2] + s_red[3];
        s_nrm = (k > 0) ? (1.0f / (sumx * sumy)) : 0.0f;  // k==0: heat = 0
    }
    __syncthreads();

    // ---- Phase 2: 8 px per thread, linear mapping ----
    int p   = ((blockIdx.x << 8) + tid) << 3;  // pixel base
    int wi0 = p & (W - 1);             // multiple of 8 -> 16B-aligned stores
    int hi  = p >> 7;                  // global row

    float hy = s_expy[hi] * s_nrm;

    // Uniform bilinear shift + weights for this slot.
    float cx = 63.5f * dx, cy = 63.5f * dy;
    float fsx = floorf(cx), fsy = floorf(cy);
    float fx = cx - fsx,    fy = cy - fsy;
    int   sxi = (int)fsx,   syi = (int)fsy;
    float wx0 = 1.0f - fx,  wx1 = fx;

    int iy0 = hi + syi, iy1 = iy0 + 1;
    float rv0 = (iy0 >= 0 && iy0 < H) ? (1.0f - fy) : 0.0f;  // wy0 * y-valid
    float rv1 = (iy1 >= 0 && iy1 < H) ? fy : 0.0f;           // wy1 * y-valid
    int cy0 = min(max(iy0, 0), H - 1);
    int cy1 = min(max(iy1, 0), H - 1);
    int c0  = wi0 + sxi;               // leftmost of the 9-column window

    const float* sb = src + (size_t)b * C * HW;

    float v[C][8];
    bool rowzero = (rv0 == 0.0f) && (rv1 == 0.0f);
    bool colzero = (c0 > W - 1) || (c0 + 8 < 0);
    if (rowzero || colzero) {
        // Entire window has zero weight/validity: no loads at all.
        #pragma unroll
        for (int ci = 0; ci < C; ci++)
            #pragma unroll
            for (int j = 0; j < 8; j++) v[ci][j] = 0.0f;
    } else if (c0 >= 0 && c0 <= W - 9) {
        // Fast path: whole 9-column window in range -> vector loads, no masks.
        #pragma unroll
        for (int ci = 0; ci < C; ci++) {
            const float* r0 = sb + ci * HW + cy0 * W + c0;
            const float* r1 = sb + ci * HW + cy1 * W + c0;
            float4a a0 = *(const float4a*)(r0);
            float4a a1 = *(const float4a*)(r0 + 4);
            float   a2 = r0[8];
            float4a b0 = *(const float4a*)(r1);
            float4a b1 = *(const float4a*)(r1 + 4);
            float   b2 = r1[8];
            float m[9];
            m[0] = rv0 * a0[0] + rv1 * b0[0];
            m[1] = rv0 * a0[1] + rv1 * b0[1];
            m[2] = rv0 * a0[2] + rv1 * b0[2];
            m[3] = rv0 * a0[3] + rv1 * b0[3];
            m[4] = rv0 * a1[0] + rv1 * b1[0];
            m[5] = rv0 * a1[1] + rv1 * b1[1];
            m[6] = rv0 * a1[2] + rv1 * b1[2];
            m[7] = rv0 * a1[3] + rv1 * b1[3];
            m[8] = rv0 * a2    + rv1 * b2;
            #pragma unroll
            for (int j = 0; j < 8; j++)
                v[ci][j] = wx0 * m[j] + wx1 * m[j + 1];
        }
    } else {
        // Edge path: clamped addresses + multiplicative masks (branch-free body).
        #pragma unroll
        for (int ci = 0; ci < C; ci++) {
            const float* r0 = sb + ci * HW + cy0 * W;
            const float* r1 = sb + ci * HW + cy1 * W;
            float m[9];
            #pragma unroll
            for (int i = 0; i < 9; i++) {
                int q = c0 + i;
                bool ok = (q >= 0) && (q < W);
                int qc = min(max(q, 0), W - 1);
                float mm = rv0 * r0[qc] + rv1 * r1[qc];
                m[i] = ok ? mm : 0.0f;
            }
            #pragma unroll
            for (int j = 0; j < 8; j++)
                v[ci][j] = wx0 * m[j] + wx1 * m[j + 1];
        }
    }

    // Heat from the rank-1 tables (no per-pixel exp).
    float4a ex0 = *(const float4a*)&s_expx[wi0];
    float4a ex1 = *(const float4a*)&s_expx[wi0 + 4];

    // out flat index: ((b*66 + k*6 + j)*D + di)*HW + hi*W + wi0 ; nt float4 stores.
    const size_t cs = (size_t)D * HW;
    size_t base = ((size_t)(b * 66 + k * 6) * D + di) * HW + (size_t)hi * W + wi0;
    float* o0 = out + base;
    nt_store4(o0 + 0,        hy*ex0[0], hy*ex0[1], hy*ex0[2], hy*ex0[3]);
    nt_store4(o0 + 4,        hy*ex1[0], hy*ex1[1], hy*ex1[2], hy*ex1[3]);
    nt_store4(o0 + cs,       dx, dx, dx, dx);
    nt_store4(o0 + cs + 4,   dx, dx, dx, dx);
    nt_store4(o0 + 2*cs,     dy, dy, dy, dy);
    nt_store4(o0 + 2*cs + 4, dy, dy, dy, dy);
    nt_store4(o0 + 3*cs,     v[0][0], v[0][1], v[0][2], v[0][3]);
    nt_store4(o0 + 3*cs + 4, v[0][4], v[0][5], v[0][6], v[0][7]);
    nt_store4(o0 + 4*cs,     v[1][0], v[1][1], v[1][2], v[1][3]);
    nt_store4(o0 + 4*cs + 4, v[1][4], v[1][5], v[1][6], v[1][7]);
    nt_store4(o0 + 5*cs,     v[2][0], v[2][1], v[2][2], v[2][3]);
    nt_store4(o0 + 5*cs + 4, v[2][4], v[2][5], v[2][6], v[2][7]);
}

extern "C" void kernel_launch(void* const* d_in, const int* in_sizes, int n_in,
                              void* d_out, int out_size, void* d_ws, size_t ws_size,
                              hipStream_t stream) {
    const float* src = (const float*)d_in[0];   // (4,3,1,128,128)
    const float* kpd = (const float*)d_in[1];   // (4,8,10,2)
    const float* kps = (const float*)d_in[2];   // (4,8,10,2)
    float* out  = (float*)d_out;                // (4,66,8,128,128)

    // 16 rows per block in x (2048 px / block at 8 px/thread), one slot per y.
    dim3 grid(HW / (256 * 8), BS * D * K1);
    memb_fused_kernel<<<grid, 256, 0, stream>>>(src, kpd, kps, out);
}

// Round 6
// 148.355 us; speedup vs baseline: 1.2504x; 1.2504x over previous
//
#include <hip/hip_runtime.h>
#include <math.h>

// Problem constants (from reference setup_inputs)
#define BS 4
#define C  3
#define D  8
#define K  10
#define K1 11
#define H  128
#define W  128
#define HW (H*W)

// 4-byte-aligned float4 for unaligned-window vector loads.
typedef float float4a __attribute__((ext_vector_type(4), aligned(4)));
// 16-byte-aligned ext-vector float4 for output stores (plain, cached:
// the 138 MB output fits in the 256 MB L3 -> nontemporal was a regression).
typedef float f4 __attribute__((ext_vector_type(4)));

__device__ __forceinline__ void store4(float* p, float a, float b, float c, float d) {
    f4 v = {a, b, c, d};
    *(f4*)p = v;
}

// Single fused kernel.
// blockIdx.y = (b*D+di)*K1 + k  (slot; kp data block-uniform)
// blockIdx.x = row-group (16 rows per block), 256 threads, 8 px/thread.
// Thread map: LINEAR pixels (p = tid*8) -> a wave covers 4 complete rows,
// so every per-channel store instruction covers 1024 B contiguous (max
// coalescing; the R2 column-group map's 128 B segments cost ~3 us).
// Phase 1 computes exp_x[128], exp_y[128] and the separable norm in LDS.
__global__ __launch_bounds__(256) void memb_fused_kernel(
        const float* __restrict__ src,
        const float* __restrict__ kpd,
        const float* __restrict__ kps,
        float* __restrict__ out) {
    __shared__ __align__(16) float s_expx[128];
    __shared__ __align__(16) float s_expy[128];
    __shared__ float s_red[4];
    __shared__ float s_nrm;

    int rk = blockIdx.y;               // 0 .. BS*D*K1-1
    int k  = rk % K1;
    int r  = rk / K1;                  // b*D + di
    int di = r & (D - 1);
    int b  = r >> 3;

    float kx = 0.f, ky = 0.f, dx = 0.f, dy = 0.f;
    if (k > 0) {
        int kidx = r * K + (k - 1);
        kx = kpd[kidx * 2 + 0];
        ky = kpd[kidx * 2 + 1];
        dx = kps[kidx * 2 + 0] - kx;
        dy = kps[kidx * 2 + 1] - ky;
    }

    int tid = threadIdx.x;

    // ---- Phase 1: Gaussian tables + normalization (separable) ----
    {
        int j = tid & 127;
        float coord = (float)j * (2.0f / 127.0f) - 1.0f;
        float dd = coord - ((tid < 128) ? kx : ky);
        float e = __expf(-50.0f * dd * dd);
        if (tid < 128) s_expx[j] = e;
        else           s_expy[j] = e;
        #pragma unroll
        for (int o = 32; o > 0; o >>= 1) e += __shfl_down(e, o, 64);
        if ((tid & 63) == 0) s_red[tid >> 6] = e;
    }
    __syncthreads();
    if (tid == 0) {
        float sumx = s_red[0] + s_red[1];
        float sumy = s_red[2] + s_red[3];
        s_nrm = (k > 0) ? (1.0f / (sumx * sumy)) : 0.0f;  // k==0: heat = 0
    }
    __syncthreads();

    // ---- Phase 2: 8 px per thread, linear mapping ----
    int p   = ((blockIdx.x << 8) + tid) << 3;  // pixel base
    int wi0 = p & (W - 1);             // multiple of 8 -> 16B-aligned stores
    int hi  = p >> 7;                  // global row

    float hy = s_expy[hi] * s_nrm;

    // Uniform bilinear shift + weights for this slot.
    float cx = 63.5f * dx, cy = 63.5f * dy;
    float fsx = floorf(cx), fsy = floorf(cy);
    float fx = cx - fsx,    fy = cy - fsy;
    int   sxi = (int)fsx,   syi = (int)fsy;
    float wx0 = 1.0f - fx,  wx1 = fx;

    int iy0 = hi + syi, iy1 = iy0 + 1;
    float rv0 = (iy0 >= 0 && iy0 < H) ? (1.0f - fy) : 0.0f;  // wy0 * y-valid
    float rv1 = (iy1 >= 0 && iy1 < H) ? fy : 0.0f;           // wy1 * y-valid
    int cy0 = min(max(iy0, 0), H - 1);
    int cy1 = min(max(iy1, 0), H - 1);
    int c0  = wi0 + sxi;               // leftmost of the 9-column window

    const float* sb = src + (size_t)b * C * HW;

    float v[C][8];
    bool rowzero = (rv0 == 0.0f) && (rv1 == 0.0f);
    bool colzero = (c0 > W - 1) || (c0 + 8 < 0);
    if (rowzero || colzero) {
        // Entire window has zero weight/validity: no loads at all.
        #pragma unroll
        for (int ci = 0; ci < C; ci++)
            #pragma unroll
            for (int j = 0; j < 8; j++) v[ci][j] = 0.0f;
    } else if (c0 >= 0 && c0 <= W - 9) {
        // Fast path: whole 9-column window in range -> vector loads, no masks.
        #pragma unroll
        for (int ci = 0; ci < C; ci++) {
            const float* r0 = sb + ci * HW + cy0 * W + c0;
            const float* r1 = sb + ci * HW + cy1 * W + c0;
            float4a a0 = *(const float4a*)(r0);
            float4a a1 = *(const float4a*)(r0 + 4);
            float   a2 = r0[8];
            float4a b0 = *(const float4a*)(r1);
            float4a b1 = *(const float4a*)(r1 + 4);
            float   b2 = r1[8];
            float m[9];
            m[0] = rv0 * a0[0] + rv1 * b0[0];
            m[1] = rv0 * a0[1] + rv1 * b0[1];
            m[2] = rv0 * a0[2] + rv1 * b0[2];
            m[3] = rv0 * a0[3] + rv1 * b0[3];
            m[4] = rv0 * a1[0] + rv1 * b1[0];
            m[5] = rv0 * a1[1] + rv1 * b1[1];
            m[6] = rv0 * a1[2] + rv1 * b1[2];
            m[7] = rv0 * a1[3] + rv1 * b1[3];
            m[8] = rv0 * a2    + rv1 * b2;
            #pragma unroll
            for (int j = 0; j < 8; j++)
                v[ci][j] = wx0 * m[j] + wx1 * m[j + 1];
        }
    } else {
        // Edge path: clamped addresses + multiplicative masks (branch-free body).
        #pragma unroll
        for (int ci = 0; ci < C; ci++) {
            const float* r0 = sb + ci * HW + cy0 * W;
            const float* r1 = sb + ci * HW + cy1 * W;
            float m[9];
            #pragma unroll
            for (int i = 0; i < 9; i++) {
                int q = c0 + i;
                bool ok = (q >= 0) && (q < W);
                int qc = min(max(q, 0), W - 1);
                float mm = rv0 * r0[qc] + rv1 * r1[qc];
                m[i] = ok ? mm : 0.0f;
            }
            #pragma unroll
            for (int j = 0; j < 8; j++)
                v[ci][j] = wx0 * m[j] + wx1 * m[j + 1];
        }
    }

    // Heat from the rank-1 tables (no per-pixel exp).
    float4a ex0 = *(const float4a*)&s_expx[wi0];
    float4a ex1 = *(const float4a*)&s_expx[wi0 + 4];

    // out flat index: ((b*66 + k*6 + j)*D + di)*HW + hi*W + wi0 ; f4 stores.
    const size_t cs = (size_t)D * HW;
    size_t base = ((size_t)(b * 66 + k * 6) * D + di) * HW + (size_t)hi * W + wi0;
    float* o0 = out + base;
    store4(o0 + 0,        hy*ex0[0], hy*ex0[1], hy*ex0[2], hy*ex0[3]);
    store4(o0 + 4,        hy*ex1[0], hy*ex1[1], hy*ex1[2], hy*ex1[3]);
    store4(o0 + cs,       dx, dx, dx, dx);
    store4(o0 + cs + 4,   dx, dx, dx, dx);
    store4(o0 + 2*cs,     dy, dy, dy, dy);
    store4(o0 + 2*cs + 4, dy, dy, dy, dy);
    store4(o0 + 3*cs,     v[0][0], v[0][1], v[0][2], v[0][3]);
    store4(o0 + 3*cs + 4, v[0][4], v[0][5], v[0][6], v[0][7]);
    store4(o0 + 4*cs,     v[1][0], v[1][1], v[1][2], v[1][3]);
    store4(o0 + 4*cs + 4, v[1][4], v[1][5], v[1][6], v[1][7]);
    store4(o0 + 5*cs,     v[2][0], v[2][1], v[2][2], v[2][3]);
    store4(o0 + 5*cs + 4, v[2][4], v[2][5], v[2][6], v[2][7]);
}

extern "C" void kernel_launch(void* const* d_in, const int* in_sizes, int n_in,
                              void* d_out, int out_size, void* d_ws, size_t ws_size,
                              hipStream_t stream) {
    const float* src = (const float*)d_in[0];   // (4,3,1,128,128)
    const float* kpd = (const float*)d_in[1];   // (4,8,10,2)
    const float* kps = (const float*)d_in[2];   // (4,8,10,2)
    float* out  = (float*)d_out;                // (4,66,8,128,128)

    // 16 rows per block in x (2048 px / block at 8 px/thread), one slot per y.
    dim3 grid(HW / (256 * 8), BS * D * K1);
    memb_fused_kernel<<<grid, 256, 0, stream>>>(src, kpd, kps, out);
}